// Round 10
// baseline (681.906 us; speedup 1.0000x reference)
//
#include <hip/hip_runtime.h>
#include <hip/hip_fp16.h>
#include <math.h>
#include <stdint.h>

#define NNZ_C 3200000
#define NN_C  100000
#define NE_C  100000
#define KD    16
#define EPSF  1e-6f
#define LSEP  0.1f

#define NBKT   800         // buckets
#define BEDG   125         // edges per bucket
#define RCAP   4480        // record capacity per bucket (mean 4000)
#define SLICES 4           // scan blocks per bucket (r8 config: best so far)

typedef unsigned int uint_t;

// ---------- workspace layout (word offsets), total ~29.9 MB ----------
#define W_PK    0                          // +50000  degree packed counters (zeroed)
#define W_CUR   50000                      // +1024   bucket cursors         (zeroed)
#define W_ACC   51024                      // +64     acc scalars            (zeroed)
#define W_S     51088                      // +1600000 S edge-major          (zeroed)
#define W_DV    (W_S + NE_C * KD)          // +100000 Dv float (fully written)
#define W_DE    (W_DV + NN_C)              // +100000 De float (fully written)
#define W_NZ    (W_DE + NN_C)              // +400000 nZ fp16 (fully written)
#define W_REC   (W_NZ + NN_C * KD / 2)     // +NBKT*RCAP records
#define W_SINK  (W_REC + NBKT * RCAP)      // +1638400 ablation sink
#define W_END   (W_SINK + NBKT * SLICES * 512)
#define W_ZERO  W_DV                       // zero pk+cur+acc+S (6.6 MB)

// Native LDS float add (no memory clobber; ordering vs flush via __syncthreads)
__device__ __forceinline__ void lds_fadd(float* p, float v) {
    asm volatile("ds_add_f32 %0, %1"
                 :
                 : "v"((uint32_t)(uintptr_t)p), "v"(v));
}

// ---- K1: degree histograms (node + edge), LDS byte-packed ------------------
__global__ __launch_bounds__(512) void k_hist(const int* __restrict__ il,
                                              uint_t* __restrict__ packed) {
    __shared__ uint_t h[12500];
    int t = threadIdx.x, b = blockIdx.x;
    int hist  = b >> 7;
    int range = (b >> 6) & 1;
    int slice = b & 63;

    for (int w = t; w < 12500; w += 512) h[w] = 0u;
    __syncthreads();

    const int4* idx4 = (const int4*)(il + (size_t)hist * NNZ_C + (size_t)slice * 50000);
    uint_t base = (uint_t)range * 50000u;
    for (int i = t; i < 12500; i += 512) {
        int4 v = idx4[i];
        uint_t u;
        u = (uint_t)v.x - base; if (u < 50000u) atomicAdd(&h[u >> 2], 1u << ((u & 3u) * 8u));
        u = (uint_t)v.y - base; if (u < 50000u) atomicAdd(&h[u >> 2], 1u << ((u & 3u) * 8u));
        u = (uint_t)v.z - base; if (u < 50000u) atomicAdd(&h[u >> 2], 1u << ((u & 3u) * 8u));
        u = (uint_t)v.w - base; if (u < 50000u) atomicAdd(&h[u >> 2], 1u << ((u & 3u) * 8u));
    }
    __syncthreads();

    uint_t* gp = packed + hist * 25000 + range * 12500;
    for (int w = t; w < 12500; w += 512) {
        uint_t v = h[w];
        if (v) atomicAdd(&gp[w], v);
    }
}

// ---- K2: unpack byte counters -> float Dv, De ------------------------------
__global__ __launch_bounds__(256) void k_unpack(const uint_t* __restrict__ packed,
                                                float* __restrict__ Dv,
                                                float* __restrict__ De) {
    int w = blockIdx.x * 256 + threadIdx.x;
    if (w < 50000) {
        uint_t v = packed[w];
        float4 f = make_float4((float)(v & 255u), (float)((v >> 8) & 255u),
                               (float)((v >> 16) & 255u), (float)(v >> 24));
        float* dst = (w < 25000) ? (Dv + (size_t)w * 4) : (De + (size_t)(w - 25000) * 4);
        *(float4*)dst = f;
    }
}

// ---- K3: nZ(fp16) = Dv^-1/2 Z, f_Dv_f partials, separation stats -----------
__global__ __launch_bounds__(256) void k_norm(const float* __restrict__ Z,
                                              const float* __restrict__ Dv,
                                              __half* __restrict__ nZh,
                                              float* __restrict__ acc) {
    __shared__ float sacc[KD + 4];
    int t = threadIdx.x;
    if (t < KD + 4) sacc[t] = 0.f;
    __syncthreads();

    int n = blockIdx.x * 256 + t;
    if (n < NN_C) {
        float dv = fmaxf(Dv[n], EPSF);
        float inv = rsqrtf(dv);
        const float4* z4 = (const float4*)(Z + (size_t)n * KD);
        float zr[KD];
        #pragma unroll
        for (int i = 0; i < 4; ++i) {
            float4 z = z4[i];
            zr[4*i+0] = z.x; zr[4*i+1] = z.y; zr[4*i+2] = z.z; zr[4*i+3] = z.w;
        }
        uint4 u[2];
        __half2* hu = (__half2*)u;
        #pragma unroll
        for (int j = 0; j < 8; ++j)
            hu[j] = __floats2half2_rn(zr[2*j] * inv, zr[2*j+1] * inv);
        uint4* o = (uint4*)(nZh + (size_t)n * KD);
        o[0] = u[0];
        o[1] = u[1];
        #pragma unroll
        for (int k = 0; k < KD; ++k) lds_fadd(&sacc[k], zr[k] * zr[k] * dv);
        float f = zr[0];
        if (f > 0.f)      { lds_fadd(&sacc[KD+0], f); lds_fadd(&sacc[KD+2], 1.f); }
        else if (f < 0.f) { lds_fadd(&sacc[KD+1], f); lds_fadd(&sacc[KD+3], 1.f); }
    }
    __syncthreads();
    if (t < KD)          unsafeAtomicAdd(&acc[16 + t], sacc[t]);
    else if (t < KD + 4) unsafeAtomicAdd(&acc[32 + (t - KD)], sacc[t]);
}

// ---- K4a: bucket pins by edge/BEDG into packed u32 records ------------------
__global__ __launch_bounds__(256) void k_bucket(const int* __restrict__ il,
                                                uint_t* __restrict__ cur,
                                                uint_t* __restrict__ recs) {
    __shared__ uint_t cnt[NBKT], bas[NBKT];
    int t = threadIdx.x;
    for (int i = t; i < NBKT; i += 256) cnt[i] = 0u;
    __syncthreads();

    int base = blockIdx.x * 4096;
    uint_t myrec[16], mybl[16];
    #pragma unroll
    for (int i = 0; i < 16; ++i) {
        int p = base + i * 256 + t;
        myrec[i] = 0xFFFFFFFFu;
        if (p < NNZ_C) {
            uint_t n = (uint_t)il[p];
            uint_t e = (uint_t)il[NNZ_C + p];
            uint_t bkt = e / BEDG;
            uint_t el  = e - bkt * BEDG;
            uint_t slot = atomicAdd(&cnt[bkt], 1u);
            myrec[i] = (n << 7) | el;
            mybl[i]  = (bkt << 16) | slot;
        }
    }
    __syncthreads();
    for (int i = t; i < NBKT; i += 256) bas[i] = cnt[i] ? atomicAdd(&cur[i], cnt[i]) : 0u;
    __syncthreads();
    #pragma unroll
    for (int i = 0; i < 16; ++i) {
        if (myrec[i] != 0xFFFFFFFFu) {
            uint_t bkt = mybl[i] >> 16, slot = mybl[i] & 0xFFFFu;
            uint_t pos = bas[bkt] + slot;
            if (pos < RCAP) recs[(size_t)bkt * RCAP + pos] = myrec[i];
        }
    }
}

// ---- K4b: per-bucket LDS accumulation; NATIVE global f32 atomic flush -------
__global__ __launch_bounds__(512) void k_scan(const uint_t* __restrict__ recs,
                                              const uint_t* __restrict__ cur,
                                              const __half* __restrict__ nZh,
                                              float* __restrict__ S) {
    __shared__ __align__(16) float Ss[BEDG * KD];   // 8 KB
    int t = threadIdx.x;
    int bkt = blockIdx.x >> 2, s = blockIdx.x & 3;

    for (int i = t; i < BEDG * KD / 4; i += 512)
        ((float4*)Ss)[i] = make_float4(0.f, 0.f, 0.f, 0.f);
    __syncthreads();

    uint_t c = cur[bkt];
    if (c > RCAP) c = RCAP;
    uint_t lo = (c * (uint_t)s) >> 2, hi = (c * (uint_t)(s + 1)) >> 2;
    const uint_t* r = recs + (size_t)bkt * RCAP;
    int k = t & 15;
    uint_t i = lo + (uint_t)(t >> 4);

    for (; i + 96 < hi; i += 128) {
        uint_t rc0 = r[i], rc1 = r[i + 32], rc2 = r[i + 64], rc3 = r[i + 96];
        float v0 = __half2float(nZh[(size_t)(rc0 >> 7) * KD + k]);
        float v1 = __half2float(nZh[(size_t)(rc1 >> 7) * KD + k]);
        float v2 = __half2float(nZh[(size_t)(rc2 >> 7) * KD + k]);
        float v3 = __half2float(nZh[(size_t)(rc3 >> 7) * KD + k]);
        lds_fadd(&Ss[(rc0 & 127u) * KD + k], v0);
        lds_fadd(&Ss[(rc1 & 127u) * KD + k], v1);
        lds_fadd(&Ss[(rc2 & 127u) * KD + k], v2);
        lds_fadd(&Ss[(rc3 & 127u) * KD + k], v3);
    }
    for (; i < hi; i += 32) {
        uint_t rc = r[i];
        float v = __half2float(nZh[(size_t)(rc >> 7) * KD + k]);
        lds_fadd(&Ss[(rc & 127u) * KD + k], v);
    }
    __syncthreads();

    // flush: native global_atomic_add_f32 (no CAS retry), coalesced
    float* gS = S + (size_t)bkt * (BEDG * KD);
    for (int j = t; j < BEDG * KD; j += 512)
        unsafeAtomicAdd(&gS[j], Ss[j]);
}

// ---- ABLATION A: record + gather legs only (no LDS atomic) ------------------
__global__ __launch_bounds__(512) void k_abl_loads(const uint_t* __restrict__ recs,
                                                   const uint_t* __restrict__ cur,
                                                   const __half* __restrict__ nZh,
                                                   float* __restrict__ sink) {
    int t = threadIdx.x;
    int bkt = blockIdx.x >> 2, s = blockIdx.x & 3;
    uint_t c = cur[bkt];
    if (c > RCAP) c = RCAP;
    uint_t lo = (c * (uint_t)s) >> 2, hi = (c * (uint_t)(s + 1)) >> 2;
    const uint_t* r = recs + (size_t)bkt * RCAP;
    int k = t & 15;
    uint_t i = lo + (uint_t)(t >> 4);
    float acc = 0.f;

    for (; i + 96 < hi; i += 128) {
        uint_t rc0 = r[i], rc1 = r[i + 32], rc2 = r[i + 64], rc3 = r[i + 96];
        float v0 = __half2float(nZh[(size_t)(rc0 >> 7) * KD + k]);
        float v1 = __half2float(nZh[(size_t)(rc1 >> 7) * KD + k]);
        float v2 = __half2float(nZh[(size_t)(rc2 >> 7) * KD + k]);
        float v3 = __half2float(nZh[(size_t)(rc3 >> 7) * KD + k]);
        acc += (v0 + v1) + (v2 + v3);
    }
    for (; i < hi; i += 32) {
        uint_t rc = r[i];
        acc += __half2float(nZh[(size_t)(rc >> 7) * KD + k]);
    }
    sink[(size_t)blockIdx.x * 512 + t] = acc;   // keeps everything live
}

// ---- ABLATION B: record + ds_add legs only (no gather) ----------------------
__global__ __launch_bounds__(512) void k_abl_ds(const uint_t* __restrict__ recs,
                                                const uint_t* __restrict__ cur,
                                                float* __restrict__ sink) {
    __shared__ __align__(16) float Ss[BEDG * KD];
    int t = threadIdx.x;
    int bkt = blockIdx.x >> 2, s = blockIdx.x & 3;

    for (int i = t; i < BEDG * KD / 4; i += 512)
        ((float4*)Ss)[i] = make_float4(0.f, 0.f, 0.f, 0.f);
    __syncthreads();

    uint_t c = cur[bkt];
    if (c > RCAP) c = RCAP;
    uint_t lo = (c * (uint_t)s) >> 2, hi = (c * (uint_t)(s + 1)) >> 2;
    const uint_t* r = recs + (size_t)bkt * RCAP;
    int k = t & 15;
    uint_t i = lo + (uint_t)(t >> 4);

    for (; i + 96 < hi; i += 128) {
        uint_t rc0 = r[i], rc1 = r[i + 32], rc2 = r[i + 64], rc3 = r[i + 96];
        lds_fadd(&Ss[(rc0 & 127u) * KD + k], (float)(rc0 >> 7));
        lds_fadd(&Ss[(rc1 & 127u) * KD + k], (float)(rc1 >> 7));
        lds_fadd(&Ss[(rc2 & 127u) * KD + k], (float)(rc2 >> 7));
        lds_fadd(&Ss[(rc3 & 127u) * KD + k], (float)(rc3 >> 7));
    }
    for (; i < hi; i += 32) {
        uint_t rc = r[i];
        lds_fadd(&Ss[(rc & 127u) * KD + k], (float)(rc >> 7));
    }
    __syncthreads();
    sink[(size_t)blockIdx.x * 512 + t] = Ss[t * 3 & 1999];
}

// ---- K4c: theta[k] = sum_e S[e,k]^2 / De[e] ---------------------------------
__global__ __launch_bounds__(256) void k_theta(const float* __restrict__ S,
                                               const float* __restrict__ De,
                                               float* __restrict__ acc) {
    __shared__ float sacc[KD];
    int t = threadIdx.x;
    if (t < KD) sacc[t] = 0.f;
    __syncthreads();
    int e = blockIdx.x * 256 + t;
    if (e < NE_C) {
        float rinv = 1.f / fmaxf(De[e], EPSF);
        const float4* s4 = (const float4*)(S + (size_t)e * KD);
        #pragma unroll
        for (int i = 0; i < 4; ++i) {
            float4 s = s4[i];
            lds_fadd(&sacc[4*i+0], s.x * s.x * rinv);
            lds_fadd(&sacc[4*i+1], s.y * s.y * rinv);
            lds_fadd(&sacc[4*i+2], s.z * s.z * rinv);
            lds_fadd(&sacc[4*i+3], s.w * s.w * rinv);
        }
    }
    __syncthreads();
    if (t < KD) unsafeAtomicAdd(&acc[t], sacc[t]);
}

// ---- K5: finalize ------------------------------------------------------------
__global__ void k_final(const float* __restrict__ acc, float* __restrict__ out) {
    if (blockIdx.x == 0 && threadIdx.x == 0) {
        float rsum = 0.f;
        #pragma unroll
        for (int k = 0; k < KD; ++k) {
            float theta = acc[k];
            float fd    = fmaxf(acc[16 + k], EPSF);
            float rq    = 1.f - theta / fd;
            if (!isfinite(rq)) rq = 0.f;
            rsum += rq;
        }
        float rl = rsum / (float)KD;
        float pS = acc[32], nS = acc[33], pC = acc[34], nC = acc[35];
        float pm = pS / fmaxf(pC, 1.f);
        float nm = nS / fmaxf(nC, 1.f);
        float sep = fabsf(pm - nm);
        float pen = (pC == 0.f || nC == 0.f) ? 1.f : 1.f / (sep + EPSF);
        out[0] = rl + LSEP * pen;
    }
}

extern "C" void kernel_launch(void* const* d_in, const int* in_sizes, int n_in,
                              void* d_out, int out_size, void* d_ws, size_t ws_size,
                              hipStream_t stream) {
    const float* Z  = (const float*)d_in[0];
    const int*   il = (const int*)d_in[1];   // (2, NNZ) int32
    float*  ws     = (float*)d_ws;
    uint_t* packed = (uint_t*)d_ws + W_PK;
    uint_t* cur    = (uint_t*)d_ws + W_CUR;
    float*  acc    = ws + W_ACC;
    float*  S      = ws + W_S;
    float*  Dv     = ws + W_DV;
    float*  De     = ws + W_DE;
    __half* nZh    = (__half*)(ws + W_NZ);
    uint_t* recs   = (uint_t*)d_ws + W_REC;
    float*  sink   = ws + W_SINK;
    float*  out    = (float*)d_out;

    hipMemsetAsync(ws, 0, (size_t)W_ZERO * sizeof(float), stream);

    k_hist  <<<256, 512, 0, stream>>>(il, packed);
    k_unpack<<<(50000 + 255) / 256, 256, 0, stream>>>(packed, Dv, De);
    k_norm  <<<(NN_C + 255) / 256, 256, 0, stream>>>(Z, Dv, nZh, acc);
    k_bucket<<<(NNZ_C + 4095) / 4096, 256, 0, stream>>>(il, cur, recs);
    k_scan  <<<NBKT * SLICES, 512, 0, stream>>>(recs, cur, nZh, S);
    k_theta <<<(NE_C + 255) / 256, 256, 0, stream>>>(S, De, acc);
    k_final <<<1, 64, 0, stream>>>(acc, out);

    // ---- diagnostics (results go to sink; timed by rocprof per-dispatch) ----
    k_abl_loads<<<NBKT * SLICES, 512, 0, stream>>>(recs, cur, nZh, sink);
    k_abl_ds   <<<NBKT * SLICES, 512, 0, stream>>>(recs, cur, sink);
}

// Round 11
// 243.796 us; speedup vs baseline: 2.7970x; 2.7970x over previous
//
#include <hip/hip_runtime.h>
#include <hip/hip_fp16.h>
#include <math.h>
#include <stdint.h>

#define NNZ_C 3200000
#define NN_C  100000
#define NE_C  100000
#define KD    16
#define EPSF  1e-6f
#define LSEP  0.1f

#define SREP  4            // S replicas (cuts same-line atomic serialization 4x)

typedef unsigned int uint_t;

// ---------- workspace layout (word offsets), total ~29.8 MB ----------
//   [W_PK, +50000)      degree packed counters u32 (node then edge)  (zeroed)
//   [W_ACC, +64)        acc: theta[0..15], fdvf[16..31], sep[32..35] (zeroed)
//   [W_S, +SREP*1.6M)   S replicas, edge-major                       (zeroed)
//   [W_DV, +100000)     Dv float (fully written by k_unpack)
//   [W_DE, +100000)     De float (fully written by k_unpack)
//   [W_NZ, +800000)     nZ fp16 (fully written by k_norm; 3.2 MB, L2-resident)
#define W_PK    0
#define W_ACC   50000
#define W_S     50064
#define W_DV    (W_S + SREP * NE_C * KD)
#define W_DE    (W_DV + NN_C)
#define W_NZ    (W_DE + NN_C)
#define W_END   (W_NZ + NN_C * KD / 2)
#define W_ZERO  W_DV        // zero pk + acc + S (25.9 MB)

// Native LDS float add (no memory clobber; ordering vs readers via __syncthreads)
__device__ __forceinline__ void lds_fadd(float* p, float v) {
    asm volatile("ds_add_f32 %0, %1"
                 :
                 : "v"((uint32_t)(uintptr_t)p), "v"(v));
}

// ---- K1: degree histograms (node + edge), LDS byte-packed ------------------
__global__ __launch_bounds__(512) void k_hist(const int* __restrict__ il,
                                              uint_t* __restrict__ packed) {
    __shared__ uint_t h[12500];
    int t = threadIdx.x, b = blockIdx.x;
    int hist  = b >> 7;          // 0 -> node (Dv), 1 -> edge (De)
    int range = (b >> 6) & 1;    // bins [range*50000, +50000)
    int slice = b & 63;          // contiguous 50K-pin slice

    for (int w = t; w < 12500; w += 512) h[w] = 0u;
    __syncthreads();

    const int4* idx4 = (const int4*)(il + (size_t)hist * NNZ_C + (size_t)slice * 50000);
    uint_t base = (uint_t)range * 50000u;
    for (int i = t; i < 12500; i += 512) {
        int4 v = idx4[i];
        uint_t u;
        u = (uint_t)v.x - base; if (u < 50000u) atomicAdd(&h[u >> 2], 1u << ((u & 3u) * 8u));
        u = (uint_t)v.y - base; if (u < 50000u) atomicAdd(&h[u >> 2], 1u << ((u & 3u) * 8u));
        u = (uint_t)v.z - base; if (u < 50000u) atomicAdd(&h[u >> 2], 1u << ((u & 3u) * 8u));
        u = (uint_t)v.w - base; if (u < 50000u) atomicAdd(&h[u >> 2], 1u << ((u & 3u) * 8u));
    }
    __syncthreads();

    uint_t* gp = packed + hist * 25000 + range * 12500;
    for (int w = t; w < 12500; w += 512) {
        uint_t v = h[w];
        if (v) atomicAdd(&gp[w], v);
    }
}

// ---- K2: unpack byte counters -> float Dv, De ------------------------------
__global__ __launch_bounds__(256) void k_unpack(const uint_t* __restrict__ packed,
                                                float* __restrict__ Dv,
                                                float* __restrict__ De) {
    int w = blockIdx.x * 256 + threadIdx.x;
    if (w < 50000) {
        uint_t v = packed[w];
        float4 f = make_float4((float)(v & 255u), (float)((v >> 8) & 255u),
                               (float)((v >> 16) & 255u), (float)(v >> 24));
        float* dst = (w < 25000) ? (Dv + (size_t)w * 4) : (De + (size_t)(w - 25000) * 4);
        *(float4*)dst = f;
    }
}

// ---- K3: nZ(fp16) = Dv^-1/2 Z, f_Dv_f partials, separation stats -----------
__global__ __launch_bounds__(256) void k_norm(const float* __restrict__ Z,
                                              const float* __restrict__ Dv,
                                              __half* __restrict__ nZh,
                                              float* __restrict__ acc) {
    __shared__ float sacc[KD + 4];
    int t = threadIdx.x;
    if (t < KD + 4) sacc[t] = 0.f;
    __syncthreads();

    int n = blockIdx.x * 256 + t;
    if (n < NN_C) {
        float dv = fmaxf(Dv[n], EPSF);
        float inv = rsqrtf(dv);
        const float4* z4 = (const float4*)(Z + (size_t)n * KD);
        float zr[KD];
        #pragma unroll
        for (int i = 0; i < 4; ++i) {
            float4 z = z4[i];
            zr[4*i+0] = z.x; zr[4*i+1] = z.y; zr[4*i+2] = z.z; zr[4*i+3] = z.w;
        }
        uint4 u[2];
        __half2* hu = (__half2*)u;
        #pragma unroll
        for (int j = 0; j < 8; ++j)
            hu[j] = __floats2half2_rn(zr[2*j] * inv, zr[2*j+1] * inv);
        uint4* o = (uint4*)(nZh + (size_t)n * KD);
        o[0] = u[0];
        o[1] = u[1];
        #pragma unroll
        for (int k = 0; k < KD; ++k) lds_fadd(&sacc[k], zr[k] * zr[k] * dv);
        float f = zr[0];
        if (f > 0.f)      { lds_fadd(&sacc[KD+0], f); lds_fadd(&sacc[KD+2], 1.f); }
        else if (f < 0.f) { lds_fadd(&sacc[KD+1], f); lds_fadd(&sacc[KD+3], 1.f); }
    }
    __syncthreads();
    if (t < KD)          unsafeAtomicAdd(&acc[16 + t], sacc[t]);
    else if (t < KD + 4) unsafeAtomicAdd(&acc[32 + (t - KD)], sacc[t]);
}

// ---- K4: one-shot scatter, thread per (pin,k), 4-way replicated S -----------
// 16 consecutive lanes share one pin -> one coalesced 32B fp16 gather and one
// 64B atomic line per pin. replica = p&3: a wave's 4 pin-groups target 4
// different replicas, cutting same-line RMW serialization 4x.
__global__ __launch_bounds__(256) void k_scatter(const int* __restrict__ il,
                                                 const __half* __restrict__ nZh,
                                                 float* __restrict__ S) {
    uint_t tid = blockIdx.x * 256u + threadIdx.x;
    if (tid < (uint_t)NNZ_C * KD) {
        uint_t p = tid >> 4, k = tid & 15u;
        int n = il[p];
        int e = il[NNZ_C + p];
        float v = __half2float(nZh[(size_t)n * KD + k]);
        unsafeAtomicAdd(&S[(size_t)(p & 3u) * (NE_C * KD) + (size_t)e * KD + k], v);
    }
}

// ---- K5: theta[k] = sum_e (sum_rep S)^2 / De[e] -----------------------------
__global__ __launch_bounds__(256) void k_theta(const float* __restrict__ S,
                                               const float* __restrict__ De,
                                               float* __restrict__ acc) {
    __shared__ float sacc[KD];
    int t = threadIdx.x;
    if (t < KD) sacc[t] = 0.f;
    __syncthreads();
    int e = blockIdx.x * 256 + t;
    if (e < NE_C) {
        float rinv = 1.f / fmaxf(De[e], EPSF);
        float4 a[4];
        #pragma unroll
        for (int rep = 0; rep < SREP; ++rep) {
            const float4* s4 = (const float4*)(S + (size_t)rep * (NE_C * KD) + (size_t)e * KD);
            #pragma unroll
            for (int i = 0; i < 4; ++i) {
                float4 x = s4[i];
                if (rep == 0) a[i] = x;
                else { a[i].x += x.x; a[i].y += x.y; a[i].z += x.z; a[i].w += x.w; }
            }
        }
        #pragma unroll
        for (int i = 0; i < 4; ++i) {
            lds_fadd(&sacc[4*i+0], a[i].x * a[i].x * rinv);
            lds_fadd(&sacc[4*i+1], a[i].y * a[i].y * rinv);
            lds_fadd(&sacc[4*i+2], a[i].z * a[i].z * rinv);
            lds_fadd(&sacc[4*i+3], a[i].w * a[i].w * rinv);
        }
    }
    __syncthreads();
    if (t < KD) unsafeAtomicAdd(&acc[t], sacc[t]);
}

// ---- K6: finalize ------------------------------------------------------------
__global__ void k_final(const float* __restrict__ acc, float* __restrict__ out) {
    if (blockIdx.x == 0 && threadIdx.x == 0) {
        float rsum = 0.f;
        #pragma unroll
        for (int k = 0; k < KD; ++k) {
            float theta = acc[k];
            float fd    = fmaxf(acc[16 + k], EPSF);
            float rq    = 1.f - theta / fd;
            if (!isfinite(rq)) rq = 0.f;
            rsum += rq;
        }
        float rl = rsum / (float)KD;
        float pS = acc[32], nS = acc[33], pC = acc[34], nC = acc[35];
        float pm = pS / fmaxf(pC, 1.f);
        float nm = nS / fmaxf(nC, 1.f);
        float sep = fabsf(pm - nm);
        float pen = (pC == 0.f || nC == 0.f) ? 1.f : 1.f / (sep + EPSF);
        out[0] = rl + LSEP * pen;
    }
}

extern "C" void kernel_launch(void* const* d_in, const int* in_sizes, int n_in,
                              void* d_out, int out_size, void* d_ws, size_t ws_size,
                              hipStream_t stream) {
    const float* Z  = (const float*)d_in[0];
    const int*   il = (const int*)d_in[1];   // (2, NNZ) int32
    float*  ws     = (float*)d_ws;
    uint_t* packed = (uint_t*)d_ws + W_PK;
    float*  acc    = ws + W_ACC;
    float*  S      = ws + W_S;
    float*  Dv     = ws + W_DV;
    float*  De     = ws + W_DE;
    __half* nZh    = (__half*)(ws + W_NZ);
    float*  out    = (float*)d_out;

    // zero packed + acc + S replicas (Dv/De/nZ fully overwritten)
    hipMemsetAsync(ws, 0, (size_t)W_ZERO * sizeof(float), stream);

    k_hist  <<<256, 512, 0, stream>>>(il, packed);
    k_unpack<<<(50000 + 255) / 256, 256, 0, stream>>>(packed, Dv, De);
    k_norm  <<<(NN_C + 255) / 256, 256, 0, stream>>>(Z, Dv, nZh, acc);
    {
        uint_t total = (uint_t)NNZ_C * KD;
        k_scatter<<<(total + 255) / 256, 256, 0, stream>>>(il, nZh, S);
    }
    k_theta <<<(NE_C + 255) / 256, 256, 0, stream>>>(S, De, acc);
    k_final <<<1, 64, 0, stream>>>(acc, out);
}

// Round 12
// 232.424 us; speedup vs baseline: 2.9339x; 1.0489x over previous
//
#include <hip/hip_runtime.h>
#include <hip/hip_fp16.h>
#include <math.h>
#include <stdint.h>

#define NNZ_C 3200000
#define NN_C  100000
#define NE_C  100000
#define KD    16
#define EPSF  1e-6f
#define LSEP  0.1f

typedef unsigned int uint_t;

// ---------- workspace layout (word offsets), total ~9.8 MB ----------
//   [W_PK, +50000)   degree packed counters u32, 4x8-bit bins
//                    (node bins in words [0,25000), edge bins [25000,50000)) (zeroed)
//   [W_ACC, +64)     acc: theta[0..15], fdvf[16..31], sep[32..35]            (zeroed)
//   [W_S, +1600000)  S edge-major fp32                                       (zeroed)
//   [W_NZ, +800000)  nZ fp16 (fully written by k_norm; 3.2 MB, L2-resident)
#define W_PK    0
#define W_ACC   50000
#define W_S     50064
#define W_NZ    (W_S + NE_C * KD)
#define W_END   (W_NZ + NN_C * KD / 2)
#define W_ZERO  W_NZ        // zero pk + acc + S (6.6 MB)

// Native LDS float add (no memory clobber; ordering vs readers via __syncthreads)
__device__ __forceinline__ void lds_fadd(float* p, float v) {
    asm volatile("ds_add_f32 %0, %1"
                 :
                 : "v"((uint32_t)(uintptr_t)p), "v"(v));
}

// byte-extract a degree count from the packed histogram
__device__ __forceinline__ float deg_from_packed(const uint_t* __restrict__ packed,
                                                 int base_word, int idx) {
    uint_t w = packed[base_word + (idx >> 2)];
    return (float)((w >> ((idx & 3) * 8)) & 255u);
}

// ---- K1: degree histograms (node + edge), LDS byte-packed ------------------
__global__ __launch_bounds__(512) void k_hist(const int* __restrict__ il,
                                              uint_t* __restrict__ packed) {
    __shared__ uint_t h[12500];
    int t = threadIdx.x, b = blockIdx.x;
    int hist  = b >> 7;          // 0 -> node (Dv), 1 -> edge (De)
    int range = (b >> 6) & 1;    // bins [range*50000, +50000)
    int slice = b & 63;          // contiguous 50K-pin slice

    for (int w = t; w < 12500; w += 512) h[w] = 0u;
    __syncthreads();

    const int4* idx4 = (const int4*)(il + (size_t)hist * NNZ_C + (size_t)slice * 50000);
    uint_t base = (uint_t)range * 50000u;
    for (int i = t; i < 12500; i += 512) {
        int4 v = idx4[i];
        uint_t u;
        u = (uint_t)v.x - base; if (u < 50000u) atomicAdd(&h[u >> 2], 1u << ((u & 3u) * 8u));
        u = (uint_t)v.y - base; if (u < 50000u) atomicAdd(&h[u >> 2], 1u << ((u & 3u) * 8u));
        u = (uint_t)v.z - base; if (u < 50000u) atomicAdd(&h[u >> 2], 1u << ((u & 3u) * 8u));
        u = (uint_t)v.w - base; if (u < 50000u) atomicAdd(&h[u >> 2], 1u << ((u & 3u) * 8u));
    }
    __syncthreads();

    uint_t* gp = packed + hist * 25000 + range * 12500;
    for (int w = t; w < 12500; w += 512) {
        uint_t v = h[w];
        if (v) atomicAdd(&gp[w], v);
    }
}

// ---- K2: nZ(fp16) = Dv^-1/2 Z, f_Dv_f partials, separation stats -----------
// Dv read as byte directly from packed counters (no unpack kernel).
__global__ __launch_bounds__(256) void k_norm(const float* __restrict__ Z,
                                              const uint_t* __restrict__ packed,
                                              __half* __restrict__ nZh,
                                              float* __restrict__ acc) {
    __shared__ float sacc[KD + 4];
    int t = threadIdx.x;
    if (t < KD + 4) sacc[t] = 0.f;
    __syncthreads();

    int n = blockIdx.x * 256 + t;
    if (n < NN_C) {
        float dv = fmaxf(deg_from_packed(packed, 0, n), EPSF);
        float inv = rsqrtf(dv);
        const float4* z4 = (const float4*)(Z + (size_t)n * KD);
        float zr[KD];
        #pragma unroll
        for (int i = 0; i < 4; ++i) {
            float4 z = z4[i];
            zr[4*i+0] = z.x; zr[4*i+1] = z.y; zr[4*i+2] = z.z; zr[4*i+3] = z.w;
        }
        uint4 u[2];
        __half2* hu = (__half2*)u;
        #pragma unroll
        for (int j = 0; j < 8; ++j)
            hu[j] = __floats2half2_rn(zr[2*j] * inv, zr[2*j+1] * inv);
        uint4* o = (uint4*)(nZh + (size_t)n * KD);
        o[0] = u[0];
        o[1] = u[1];
        #pragma unroll
        for (int k = 0; k < KD; ++k) lds_fadd(&sacc[k], zr[k] * zr[k] * dv);
        float f = zr[0];
        if (f > 0.f)      { lds_fadd(&sacc[KD+0], f); lds_fadd(&sacc[KD+2], 1.f); }
        else if (f < 0.f) { lds_fadd(&sacc[KD+1], f); lds_fadd(&sacc[KD+3], 1.f); }
    }
    __syncthreads();
    if (t < KD)          unsafeAtomicAdd(&acc[16 + t], sacc[t]);
    else if (t < KD + 4) unsafeAtomicAdd(&acc[32 + (t - KD)], sacc[t]);
}

// ---- K3: one-shot scatter, thread per (pin,k) -------------------------------
// 16 consecutive lanes share one pin -> one coalesced 32B fp16 gather and one
// 64B atomic line per pin. 3.2M line-RMWs at the measured ~20 G/s device
// atomic rate = the 163 us wall.
__global__ __launch_bounds__(256) void k_scatter(const int* __restrict__ il,
                                                 const __half* __restrict__ nZh,
                                                 float* __restrict__ S) {
    uint_t tid = blockIdx.x * 256u + threadIdx.x;
    if (tid < (uint_t)NNZ_C * KD) {
        uint_t p = tid >> 4, k = tid & 15u;
        int n = il[p];
        int e = il[NNZ_C + p];
        float v = __half2float(nZh[(size_t)n * KD + k]);
        unsafeAtomicAdd(&S[(size_t)e * KD + k], v);
    }
}

// ---- K4: theta[k] = sum_e S[e,k]^2 / De[e] ----------------------------------
// De read as byte from packed counters (edge section starts at word 25000).
__global__ __launch_bounds__(256) void k_theta(const float* __restrict__ S,
                                               const uint_t* __restrict__ packed,
                                               float* __restrict__ acc) {
    __shared__ float sacc[KD];
    int t = threadIdx.x;
    if (t < KD) sacc[t] = 0.f;
    __syncthreads();
    int e = blockIdx.x * 256 + t;
    if (e < NE_C) {
        float rinv = 1.f / fmaxf(deg_from_packed(packed, 25000, e), EPSF);
        const float4* s4 = (const float4*)(S + (size_t)e * KD);
        #pragma unroll
        for (int i = 0; i < 4; ++i) {
            float4 s = s4[i];
            lds_fadd(&sacc[4*i+0], s.x * s.x * rinv);
            lds_fadd(&sacc[4*i+1], s.y * s.y * rinv);
            lds_fadd(&sacc[4*i+2], s.z * s.z * rinv);
            lds_fadd(&sacc[4*i+3], s.w * s.w * rinv);
        }
    }
    __syncthreads();
    if (t < KD) unsafeAtomicAdd(&acc[t], sacc[t]);
}

// ---- K5: finalize ------------------------------------------------------------
__global__ void k_final(const float* __restrict__ acc, float* __restrict__ out) {
    if (blockIdx.x == 0 && threadIdx.x == 0) {
        float rsum = 0.f;
        #pragma unroll
        for (int k = 0; k < KD; ++k) {
            float theta = acc[k];
            float fd    = fmaxf(acc[16 + k], EPSF);
            float rq    = 1.f - theta / fd;
            if (!isfinite(rq)) rq = 0.f;
            rsum += rq;
        }
        float rl = rsum / (float)KD;
        float pS = acc[32], nS = acc[33], pC = acc[34], nC = acc[35];
        float pm = pS / fmaxf(pC, 1.f);
        float nm = nS / fmaxf(nC, 1.f);
        float sep = fabsf(pm - nm);
        float pen = (pC == 0.f || nC == 0.f) ? 1.f : 1.f / (sep + EPSF);
        out[0] = rl + LSEP * pen;
    }
}

extern "C" void kernel_launch(void* const* d_in, const int* in_sizes, int n_in,
                              void* d_out, int out_size, void* d_ws, size_t ws_size,
                              hipStream_t stream) {
    const float* Z  = (const float*)d_in[0];
    const int*   il = (const int*)d_in[1];   // (2, NNZ) int32
    float*  ws     = (float*)d_ws;
    uint_t* packed = (uint_t*)d_ws + W_PK;
    float*  acc    = ws + W_ACC;
    float*  S      = ws + W_S;
    __half* nZh    = (__half*)(ws + W_NZ);
    float*  out    = (float*)d_out;

    // zero packed + acc + S (nZ fully overwritten; S must be re-zeroed every
    // call because the scatter accumulates with +=)
    hipMemsetAsync(ws, 0, (size_t)W_ZERO * sizeof(float), stream);

    k_hist  <<<256, 512, 0, stream>>>(il, packed);
    k_norm  <<<(NN_C + 255) / 256, 256, 0, stream>>>(Z, packed, nZh, acc);
    {
        uint_t total = (uint_t)NNZ_C * KD;
        k_scatter<<<(total + 255) / 256, 256, 0, stream>>>(il, nZh, S);
    }
    k_theta <<<(NE_C + 255) / 256, 256, 0, stream>>>(S, packed, acc);
    k_final <<<1, 64, 0, stream>>>(acc, out);
}